// Round 5
// baseline (294.216 us; speedup 1.0000x reference)
//
#include <hip/hip_runtime.h>
#include <hip/hip_bf16.h>

typedef __attribute__((ext_vector_type(8))) short bf16x8;
typedef __attribute__((ext_vector_type(4))) float f32x4;

__device__ __forceinline__ unsigned int rne_pack(float s0, float s1) {
    unsigned int b0 = __float_as_uint(s0), b1 = __float_as_uint(s1);
    b0 += 0x7fffu + ((b0 >> 16) & 1);
    b1 += 0x7fffu + ((b1 >> 16) & 1);
    return (b0 >> 16) | (b1 & 0xffff0000u);
}
__device__ __forceinline__ float ubf(unsigned short u) {
    return __uint_as_float(((unsigned int)u) << 16);
}

// ---------------- x -> bf16 copy (for deform gather) ----------------
__global__ __launch_bounds__(256) void convert_x_bf16(const float* __restrict__ x,
                                                      unsigned short* __restrict__ x16) {
    int idx = blockIdx.x * 256 + threadIdx.x;      // 2097152/4 = 524288 float4s
    float4 v = ((const float4*)x)[idx];
    unsigned int lo = rne_pack(v.x, v.y), hi = rne_pack(v.z, v.w);
    ((uint2*)x16)[idx] = make_uint2(lo, hi);
}

// ---------------- weight transposes ----------------
// dweights [4][256][256][3][3] fp32 -> wTb [i][k][o][c] bf16
__global__ __launch_bounds__(256) void transpose_dw_bf16(const float* __restrict__ dw,
                                                         __hip_bfloat16* __restrict__ wTb) {
    int idx = blockIdx.x * 256 + threadIdx.x;      // 2359296
    int c = idx & 255;
    int o = (idx >> 8) & 255;
    int rest = idx >> 16;                          // i*9 + k
    int k = rest % 9, i = rest / 9;
    wTb[idx] = __float2bfloat16(dw[(((i << 8) + o) * 256 + c) * 9 + k]);
}

// oweights [4][18][256][3][3] fp32 -> owTb [r][k][32][256] bf16 (rows 18..31 zero)
__global__ __launch_bounds__(256) void transpose_ow_bf16(const float* __restrict__ ow,
                                                         __hip_bfloat16* __restrict__ owTb) {
    int idx = blockIdx.x * 256 + threadIdx.x;      // 294912
    int c = idx & 255;
    int m = (idx >> 8) & 31;
    int rk = idx >> 13;
    int k = rk % 9, r = rk / 9;
    float v = (m < 18) ? ow[((r * 18 + m) * 256 + c) * 9 + k] : 0.f;
    owTb[idx] = __float2bfloat16(v);
}

// ---------------- offset conv as bf16-MFMA implicit GEMM (verbatim r4, verified) ----------------
__global__ __launch_bounds__(512) void offset_mfma(const float* __restrict__ x,
                                                   const __hip_bfloat16* __restrict__ owTb,
                                                   const float* __restrict__ obias,
                                                   float* __restrict__ off) {
    __shared__ short s_a[4][32][8];
    __shared__ short s_b[4][128][8];
    __shared__ int   s_pix[9][128];
    __shared__ float s_msk[9][128];

    const int blk = blockIdx.x;
    const int r = (blk & 7) >> 1, b = blk & 1;
    const int px0 = (blk >> 3) << 7;
    const int rate = 6 * (r + 1);

    const int tid = threadIdx.x;
    const int lane = tid & 63;
    const int w = tid >> 6;
    const int kg = lane >> 4, lm = lane & 15;
    const int sg = tid >> 7, spx = tid & 127;
    const int mA = (tid & 127) >> 2, kgA = tid & 3;

    const float* xb = x + (size_t)b * 256 * 4096;
    const unsigned short* wrb = (const unsigned short*)owTb + (size_t)r * 9 * 32 * 256;

    for (int e = tid; e < 1152; e += 512) {
        int k = e >> 7, pl = e & 127;
        int pg = px0 + pl;
        int yy = (pg >> 6) + (k / 3 - 1) * rate;
        int xx = (pg & 63) + (k % 3 - 1) * rate;
        bool v = ((unsigned)yy < 64u) && ((unsigned)xx < 64u);
        int cy = min(max(yy, 0), 63), cx = min(max(xx, 0), 63);
        s_pix[k][pl] = cy * 64 + cx;
        s_msk[k][pl] = v ? 1.f : 0.f;
    }
    __syncthreads();

    f32x4 acc0 = (f32x4)(0.f), acc1 = (f32x4)(0.f);

    for (int t = 0; t < 72; ++t) {
        const int tap = t >> 3;
        const int c0 = (t & 7) << 5;

        uint4 a;
        if (tid < 128)
            a = *(const uint4*)(wrb + ((size_t)tap * 32 + mA) * 256 + c0 + kgA * 8);

        int pix = s_pix[tap][spx];
        float msk = s_msk[tap][spx];
        const float* xc = xb + (size_t)(c0 + sg * 8) * 4096;
        float sv[8];
#pragma unroll
        for (int j = 0; j < 8; ++j)
            sv[j] = xc[(size_t)j * 4096 + pix] * msk;
        uint4 pk = make_uint4(rne_pack(sv[0], sv[1]), rne_pack(sv[2], sv[3]),
                              rne_pack(sv[4], sv[5]), rne_pack(sv[6], sv[7]));

        __syncthreads();
        if (tid < 128) *(uint4*)&s_a[kgA][mA][0] = a;
        *(uint4*)&s_b[sg][spx][0] = pk;
        __syncthreads();

        bf16x8 bf  = *(const bf16x8*)&s_b[kg][w * 16 + lm][0];
        bf16x8 af0 = *(const bf16x8*)&s_a[kg][lm][0];
        bf16x8 af1 = *(const bf16x8*)&s_a[kg][16 + lm][0];
        acc0 = __builtin_amdgcn_mfma_f32_16x16x32_bf16(af0, bf, acc0, 0, 0, 0);
        acc1 = __builtin_amdgcn_mfma_f32_16x16x32_bf16(af1, bf, acc1, 0, 0, 0);
    }

    const float* bias = obias + r * 18;
    float* ob = off + (size_t)(r * 2 + b) * 18 * 4096;
    int px = px0 + w * 16 + lm;
#pragma unroll
    for (int reg = 0; reg < 4; ++reg) {
        int m = kg * 4 + reg;
        ob[(size_t)m * 4096 + px] = fmaxf(acc0[reg] + bias[m], 0.f);
        int m1 = 16 + m;
        if (m1 < 18)
            ob[(size_t)m1 * 4096 + px] = fmaxf(acc1[reg] + bias[m1], 0.f);
    }
}

// ---------------- deformable conv v3: bf16 gather, coalesced+swizzled A, 2 blocks/CU ----------------
// grid: 512 blocks; blk&7 = (i,b), blk>>3 = 64-px tile (one row). 512 threads = 8 waves.
// Tile: 256o x 64px, K-step 64 (tap x 64ch), 36 steps, 2 barriers/step.
__global__ __launch_bounds__(512, 4) void deform_mfma3(const unsigned short* __restrict__ x16,
                                                       const __hip_bfloat16* __restrict__ wTb,
                                                       const float* __restrict__ off,
                                                       float* __restrict__ out) {
    __shared__ short  s_a[256][64];     // [o][64 step-ch], col ^= (o&7)*8 swizzle  32 KB
    __shared__ short  s_b[8][64][8];    // [octet][px][8ch]                          8 KB
    __shared__ int4   s_pix[9][64];
    __shared__ float4 s_wt[9][64];

    const int blk = blockIdx.x;
    const int i = (blk & 7) >> 1, b = blk & 1;
    const int px0 = (blk >> 3) << 6;
    const int r = (i + 3) & 3;
    const int rate = 6 * (i + 1);

    const int tid = threadIdx.x;
    const int lane = tid & 63;
    const int w = tid >> 6;
    const int wo = w >> 1, wp = w & 1;          // o-quarter (64), px-half (32)
    const int kg = lane >> 4, lm = lane & 15;
    const int kgB = tid >> 6, pxB = tid & 63;   // B staging: octet, pixel

    const unsigned short* xb = x16 + (size_t)b * 1048576;
    const float* offb = off + (size_t)(r * 2 + b) * 18 * 4096;
    const unsigned short* wib = (const unsigned short*)wTb + (size_t)i * 9 * 65536;

    // bilinear coords/weights: 9 taps x 64 px
    for (int e = tid; e < 576; e += 512) {
        int k = e >> 6, pl = e & 63;
        int pg = px0 + pl;
        int yy = pg >> 6, xc = pg & 63;
        float dy = offb[(size_t)(2 * k) * 4096 + pg];
        float dx = offb[(size_t)(2 * k + 1) * 4096 + pg];
        float py = (float)(yy + (k / 3 - 1) * rate) + dy;
        float pxf = (float)(xc + (k % 3 - 1) * rate) + dx;
        float fy = floorf(py), fx = floorf(pxf);
        int y0 = (int)fy, x0 = (int)fx;
        float wy = py - fy, wx = pxf - fx;
        float vy0 = ((unsigned)y0 < 64u) ? 1.f : 0.f;
        float vy1 = ((unsigned)(y0 + 1) < 64u) ? 1.f : 0.f;
        float vx0 = ((unsigned)x0 < 64u) ? 1.f : 0.f;
        float vx1 = ((unsigned)(x0 + 1) < 64u) ? 1.f : 0.f;
        int cy0 = min(max(y0, 0), 63), cy1 = min(max(y0 + 1, 0), 63);
        int cx0 = min(max(x0, 0), 63), cx1 = min(max(x0 + 1, 0), 63);
        s_pix[k][pl] = make_int4(cy0 * 64 + cx0, cy0 * 64 + cx1,
                                 cy1 * 64 + cx0, cy1 * 64 + cx1);
        s_wt[k][pl] = make_float4(vy0 * vx0 * (1.f - wy) * (1.f - wx),
                                  vy0 * vx1 * (1.f - wy) * wx,
                                  vy1 * vx0 * wy * (1.f - wx),
                                  vy1 * vx1 * wy * wx);
    }
    __syncthreads();

    f32x4 acc[4][2];
#pragma unroll
    for (int mi = 0; mi < 4; ++mi) {
        acc[mi][0] = (f32x4)(0.f);
        acc[mi][1] = (f32x4)(0.f);
    }

    for (int t = 0; t < 36; ++t) {
        const int tap = t >> 2;
        const int c0 = (t & 3) << 6;

        // -- A: 4 coalesced uint4 loads (8 lanes cover contiguous 128 B) --
        uint4 a[4];
        const unsigned short* wrow = wib + (size_t)tap * 65536 + c0;
#pragma unroll
        for (int q = 0; q < 4; ++q) {
            int u = tid + q * 512;
            a[q] = *(const uint4*)(wrow + (size_t)(u >> 3) * 256 + (u & 7) * 8);
        }

        // -- B: bilinear gather of 8 channels from bf16 x --
        int4 p = s_pix[tap][pxB];
        float4 qw = s_wt[tap][pxB];
        const unsigned short* xc = xb + (size_t)(c0 + kgB * 8) * 4096;
        unsigned int pk[4];
#pragma unroll
        for (int h = 0; h < 2; ++h) {
            float sv[4];
#pragma unroll
            for (int j = 0; j < 4; ++j) {
                const unsigned short* xcj = xc + (size_t)(h * 4 + j) * 4096;
                float v00 = ubf(xcj[p.x]), v01 = ubf(xcj[p.y]);
                float v10 = ubf(xcj[p.z]), v11 = ubf(xcj[p.w]);
                sv[j] = v00 * qw.x + v01 * qw.y + v10 * qw.z + v11 * qw.w;
            }
            pk[2 * h]     = rne_pack(sv[0], sv[1]);
            pk[2 * h + 1] = rne_pack(sv[2], sv[3]);
        }

        __syncthreads();
#pragma unroll
        for (int q = 0; q < 4; ++q) {
            int u = tid + q * 512;
            int o = u >> 3, part = u & 7;
            int col = (part * 8) ^ ((o & 7) * 8);
            *(uint4*)&s_a[o][col] = a[q];
        }
        *(uint2*)&s_b[kgB][pxB][0] = make_uint2(pk[0], pk[1]);
        *(uint2*)&s_b[kgB][pxB][4] = make_uint2(pk[2], pk[3]);
        __syncthreads();

#pragma unroll
        for (int kf = 0; kf < 2; ++kf) {
            int oct = kf * 4 + kg;
            bf16x8 bf0 = *(const bf16x8*)&s_b[oct][wp * 32 + lm][0];
            bf16x8 bf1 = *(const bf16x8*)&s_b[oct][wp * 32 + 16 + lm][0];
#pragma unroll
            for (int mi = 0; mi < 4; ++mi) {
                int o = wo * 64 + mi * 16 + lm;
                int col = (oct * 8) ^ ((o & 7) * 8);
                bf16x8 af = *(const bf16x8*)&s_a[o][col];
                acc[mi][0] = __builtin_amdgcn_mfma_f32_16x16x32_bf16(af, bf0, acc[mi][0], 0, 0, 0);
                acc[mi][1] = __builtin_amdgcn_mfma_f32_16x16x32_bf16(af, bf1, acc[mi][1], 0, 0, 0);
            }
        }
    }

    // epilogue: C/D col = lane&15 (px), row = kg*4 + reg (o)
    float* ob = out + ((size_t)b * 1024 + i * 256) * 4096;
#pragma unroll
    for (int mi = 0; mi < 4; ++mi) {
        int o = wo * 64 + mi * 16 + kg * 4;
#pragma unroll
        for (int ni = 0; ni < 2; ++ni) {
            int pg = px0 + wp * 32 + ni * 16 + lm;
#pragma unroll
            for (int reg = 0; reg < 4; ++reg)
                ob[(size_t)(o + reg) * 4096 + pg] = acc[mi][ni][reg];
        }
    }
}

extern "C" void kernel_launch(void* const* d_in, const int* in_sizes, int n_in,
                              void* d_out, int out_size, void* d_ws, size_t ws_size,
                              hipStream_t stream) {
    const float* x  = (const float*)d_in[0];   // [2,256,64,64]
    const float* dw = (const float*)d_in[1];   // [4,256,256,3,3]
    const float* ow = (const float*)d_in[2];   // [4,18,256,3,3]
    const float* ob = (const float*)d_in[3];   // [4,18]
    float* out = (float*)d_out;                // [2,1024,64,64]

    float* ws  = (float*)d_ws;
    float* off = ws;                                        // 589824 f32
    __hip_bfloat16* wTb  = (__hip_bfloat16*)(ws + 589824);  // 2359296 bf16
    __hip_bfloat16* owTb = wTb + 2359296;                   // 294912 bf16
    unsigned short* x16  = (unsigned short*)(ws + 1916928); // 2097152 bf16

    convert_x_bf16<<<2048, 256, 0, stream>>>(x, x16);
    transpose_dw_bf16<<<9216, 256, 0, stream>>>(dw, wTb);
    transpose_ow_bf16<<<1152, 256, 0, stream>>>(ow, owTb);
    offset_mfma<<<256, 512, 0, stream>>>(x, owTb, ob, off);
    deform_mfma3<<<512, 512, 0, stream>>>(x16, wTb, off, out);
}

// Round 6
// 293.751 us; speedup vs baseline: 1.0016x; 1.0016x over previous
//
#include <hip/hip_runtime.h>
#include <hip/hip_bf16.h>

typedef __attribute__((ext_vector_type(8))) short bf16x8;
typedef __attribute__((ext_vector_type(4))) float f32x4;

__device__ __forceinline__ unsigned int rne_pack(float s0, float s1) {
    unsigned int b0 = __float_as_uint(s0), b1 = __float_as_uint(s1);
    b0 += 0x7fffu + ((b0 >> 16) & 1);
    b1 += 0x7fffu + ((b1 >> 16) & 1);
    return (b0 >> 16) | (b1 & 0xffff0000u);
}
__device__ __forceinline__ float ubf(unsigned short u) {
    return __uint_as_float(((unsigned int)u) << 16);
}

// ---------------- x -> bf16 copy (for deform gather) ----------------
__global__ __launch_bounds__(256) void convert_x_bf16(const float* __restrict__ x,
                                                      unsigned short* __restrict__ x16) {
    int idx = blockIdx.x * 256 + threadIdx.x;      // 524288 float4s
    float4 v = ((const float4*)x)[idx];
    unsigned int lo = rne_pack(v.x, v.y), hi = rne_pack(v.z, v.w);
    ((uint2*)x16)[idx] = make_uint2(lo, hi);
}

// ---------------- weight transposes ----------------
// dweights [4][256][256][3][3] fp32 -> wTb [i][k][o][c] bf16
__global__ __launch_bounds__(256) void transpose_dw_bf16(const float* __restrict__ dw,
                                                         __hip_bfloat16* __restrict__ wTb) {
    int idx = blockIdx.x * 256 + threadIdx.x;      // 2359296
    int c = idx & 255;
    int o = (idx >> 8) & 255;
    int rest = idx >> 16;                          // i*9 + k
    int k = rest % 9, i = rest / 9;
    wTb[idx] = __float2bfloat16(dw[(((i << 8) + o) * 256 + c) * 9 + k]);
}

// oweights [4][18][256][3][3] fp32 -> owTb [r][k][32][256] bf16 (rows 18..31 zero)
__global__ __launch_bounds__(256) void transpose_ow_bf16(const float* __restrict__ ow,
                                                         __hip_bfloat16* __restrict__ owTb) {
    int idx = blockIdx.x * 256 + threadIdx.x;      // 294912
    int c = idx & 255;
    int m = (idx >> 8) & 31;
    int rk = idx >> 13;
    int k = rk % 9, r = rk / 9;
    float v = (m < 18) ? ow[((r * 18 + m) * 256 + c) * 9 + k] : 0.f;
    owTb[idx] = __float2bfloat16(v);
}

// ---------------- offset conv as bf16-MFMA implicit GEMM (verified r4) ----------------
__global__ __launch_bounds__(512) void offset_mfma(const float* __restrict__ x,
                                                   const __hip_bfloat16* __restrict__ owTb,
                                                   const float* __restrict__ obias,
                                                   float* __restrict__ off) {
    __shared__ short s_a[4][32][8];
    __shared__ short s_b[4][128][8];
    __shared__ int   s_pix[9][128];
    __shared__ float s_msk[9][128];

    const int blk = blockIdx.x;
    const int r = (blk & 7) >> 1, b = blk & 1;
    const int px0 = (blk >> 3) << 7;
    const int rate = 6 * (r + 1);

    const int tid = threadIdx.x;
    const int lane = tid & 63;
    const int w = tid >> 6;
    const int kg = lane >> 4, lm = lane & 15;
    const int sg = tid >> 7, spx = tid & 127;
    const int mA = (tid & 127) >> 2, kgA = tid & 3;

    const float* xb = x + (size_t)b * 256 * 4096;
    const unsigned short* wrb = (const unsigned short*)owTb + (size_t)r * 9 * 32 * 256;

    for (int e = tid; e < 1152; e += 512) {
        int k = e >> 7, pl = e & 127;
        int pg = px0 + pl;
        int yy = (pg >> 6) + (k / 3 - 1) * rate;
        int xx = (pg & 63) + (k % 3 - 1) * rate;
        bool v = ((unsigned)yy < 64u) && ((unsigned)xx < 64u);
        int cy = min(max(yy, 0), 63), cx = min(max(xx, 0), 63);
        s_pix[k][pl] = cy * 64 + cx;
        s_msk[k][pl] = v ? 1.f : 0.f;
    }
    __syncthreads();

    f32x4 acc0 = (f32x4)(0.f), acc1 = (f32x4)(0.f);

    for (int t = 0; t < 72; ++t) {
        const int tap = t >> 3;
        const int c0 = (t & 7) << 5;

        uint4 a;
        if (tid < 128)
            a = *(const uint4*)(wrb + ((size_t)tap * 32 + mA) * 256 + c0 + kgA * 8);

        int pix = s_pix[tap][spx];
        float msk = s_msk[tap][spx];
        const float* xc = xb + (size_t)(c0 + sg * 8) * 4096;
        float sv[8];
#pragma unroll
        for (int j = 0; j < 8; ++j)
            sv[j] = xc[(size_t)j * 4096 + pix] * msk;
        uint4 pk = make_uint4(rne_pack(sv[0], sv[1]), rne_pack(sv[2], sv[3]),
                              rne_pack(sv[4], sv[5]), rne_pack(sv[6], sv[7]));

        __syncthreads();
        if (tid < 128) *(uint4*)&s_a[kgA][mA][0] = a;
        *(uint4*)&s_b[sg][spx][0] = pk;
        __syncthreads();

        bf16x8 bf  = *(const bf16x8*)&s_b[kg][w * 16 + lm][0];
        bf16x8 af0 = *(const bf16x8*)&s_a[kg][lm][0];
        bf16x8 af1 = *(const bf16x8*)&s_a[kg][16 + lm][0];
        acc0 = __builtin_amdgcn_mfma_f32_16x16x32_bf16(af0, bf, acc0, 0, 0, 0);
        acc1 = __builtin_amdgcn_mfma_f32_16x16x32_bf16(af1, bf, acc1, 0, 0, 0);
    }

    const float* bias = obias + r * 18;
    float* ob = off + (size_t)(r * 2 + b) * 18 * 4096;
    int px = px0 + w * 16 + lm;
#pragma unroll
    for (int reg = 0; reg < 4; ++reg) {
        int m = kg * 4 + reg;
        ob[(size_t)m * 4096 + px] = fmaxf(acc0[reg] + bias[m], 0.f);
        int m1 = 16 + m;
        if (m1 < 18)
            ob[(size_t)m1 * 4096 + px] = fmaxf(acc1[reg] + bias[m1], 0.f);
    }
}

// ---------------- deformable conv v3: bf16 gather, coalesced+swizzled A ----------------
// grid: 512 blocks; blk&7 = (i,b), blk>>3 = 64-px tile (one row). 512 threads = 8 waves.
// Tile: 256o x 64px, K-step 64 (tap x 64ch), 36 steps, 2 barriers/step.
// launch_bounds min-waves = 2: spill-free VGPR budget (round-5 lesson: 4 forced
// a 64-VGPR cap -> 495 MB of scratch spill traffic).
__global__ __launch_bounds__(512, 2) void deform_mfma3(const unsigned short* __restrict__ x16,
                                                       const __hip_bfloat16* __restrict__ wTb,
                                                       const float* __restrict__ off,
                                                       float* __restrict__ out) {
    __shared__ short  s_a[256][64];     // [o][64 step-ch], col ^= (o&7)*8 swizzle  32 KB
    __shared__ short  s_b[8][64][8];    // [octet][px][8ch]                          8 KB
    __shared__ int4   s_pix[9][64];
    __shared__ float4 s_wt[9][64];

    const int blk = blockIdx.x;
    const int i = (blk & 7) >> 1, b = blk & 1;
    const int px0 = (blk >> 3) << 6;
    const int r = (i + 3) & 3;
    const int rate = 6 * (i + 1);

    const int tid = threadIdx.x;
    const int lane = tid & 63;
    const int w = tid >> 6;
    const int wo = w >> 1, wp = w & 1;          // o-quarter (64), px-half (32)
    const int kg = lane >> 4, lm = lane & 15;
    const int kgB = tid >> 6, pxB = tid & 63;   // B staging: octet, pixel

    const unsigned short* xb = x16 + (size_t)b * 1048576;
    const float* offb = off + (size_t)(r * 2 + b) * 18 * 4096;
    const unsigned short* wib = (const unsigned short*)wTb + (size_t)i * 9 * 65536;

    // bilinear coords/weights: 9 taps x 64 px
    for (int e = tid; e < 576; e += 512) {
        int k = e >> 6, pl = e & 63;
        int pg = px0 + pl;
        int yy = pg >> 6, xc = pg & 63;
        float dy = offb[(size_t)(2 * k) * 4096 + pg];
        float dx = offb[(size_t)(2 * k + 1) * 4096 + pg];
        float py = (float)(yy + (k / 3 - 1) * rate) + dy;
        float pxf = (float)(xc + (k % 3 - 1) * rate) + dx;
        float fy = floorf(py), fx = floorf(pxf);
        int y0 = (int)fy, x0 = (int)fx;
        float wy = py - fy, wx = pxf - fx;
        float vy0 = ((unsigned)y0 < 64u) ? 1.f : 0.f;
        float vy1 = ((unsigned)(y0 + 1) < 64u) ? 1.f : 0.f;
        float vx0 = ((unsigned)x0 < 64u) ? 1.f : 0.f;
        float vx1 = ((unsigned)(x0 + 1) < 64u) ? 1.f : 0.f;
        int cy0 = min(max(y0, 0), 63), cy1 = min(max(y0 + 1, 0), 63);
        int cx0 = min(max(x0, 0), 63), cx1 = min(max(x0 + 1, 0), 63);
        s_pix[k][pl] = make_int4(cy0 * 64 + cx0, cy0 * 64 + cx1,
                                 cy1 * 64 + cx0, cy1 * 64 + cx1);
        s_wt[k][pl] = make_float4(vy0 * vx0 * (1.f - wy) * (1.f - wx),
                                  vy0 * vx1 * (1.f - wy) * wx,
                                  vy1 * vx0 * wy * (1.f - wx),
                                  vy1 * vx1 * wy * wx);
    }
    __syncthreads();

    f32x4 acc[4][2];
#pragma unroll
    for (int mi = 0; mi < 4; ++mi) {
        acc[mi][0] = (f32x4)(0.f);
        acc[mi][1] = (f32x4)(0.f);
    }

    for (int t = 0; t < 36; ++t) {
        const int tap = t >> 2;
        const int c0 = (t & 3) << 6;

        // -- A: 4 coalesced uint4 loads (8 lanes cover contiguous 128 B) --
        uint4 a[4];
        const unsigned short* wrow = wib + (size_t)tap * 65536 + c0;
#pragma unroll
        for (int q = 0; q < 4; ++q) {
            int u = tid + q * 512;
            a[q] = *(const uint4*)(wrow + (size_t)(u >> 3) * 256 + (u & 7) * 8);
        }

        // -- B: bilinear gather of 8 channels from bf16 x --
        int4 p = s_pix[tap][pxB];
        float4 qw = s_wt[tap][pxB];
        const unsigned short* xc = xb + (size_t)(c0 + kgB * 8) * 4096;
        unsigned int pk[4];
#pragma unroll
        for (int h = 0; h < 2; ++h) {
            float sv[4];
#pragma unroll
            for (int j = 0; j < 4; ++j) {
                const unsigned short* xcj = xc + (size_t)(h * 4 + j) * 4096;
                float v00 = ubf(xcj[p.x]), v01 = ubf(xcj[p.y]);
                float v10 = ubf(xcj[p.z]), v11 = ubf(xcj[p.w]);
                sv[j] = v00 * qw.x + v01 * qw.y + v10 * qw.z + v11 * qw.w;
            }
            pk[2 * h]     = rne_pack(sv[0], sv[1]);
            pk[2 * h + 1] = rne_pack(sv[2], sv[3]);
        }

        __syncthreads();
#pragma unroll
        for (int q = 0; q < 4; ++q) {
            int u = tid + q * 512;
            int o = u >> 3, part = u & 7;
            int col = (part * 8) ^ ((o & 7) * 8);
            *(uint4*)&s_a[o][col] = a[q];
        }
        *(uint2*)&s_b[kgB][pxB][0] = make_uint2(pk[0], pk[1]);
        *(uint2*)&s_b[kgB][pxB][4] = make_uint2(pk[2], pk[3]);
        __syncthreads();

#pragma unroll
        for (int kf = 0; kf < 2; ++kf) {
            int oct = kf * 4 + kg;
            bf16x8 bf0 = *(const bf16x8*)&s_b[oct][wp * 32 + lm][0];
            bf16x8 bf1 = *(const bf16x8*)&s_b[oct][wp * 32 + 16 + lm][0];
#pragma unroll
            for (int mi = 0; mi < 4; ++mi) {
                int o = wo * 64 + mi * 16 + lm;
                int col = (oct * 8) ^ ((o & 7) * 8);
                bf16x8 af = *(const bf16x8*)&s_a[o][col];
                acc[mi][0] = __builtin_amdgcn_mfma_f32_16x16x32_bf16(af, bf0, acc[mi][0], 0, 0, 0);
                acc[mi][1] = __builtin_amdgcn_mfma_f32_16x16x32_bf16(af, bf1, acc[mi][1], 0, 0, 0);
            }
        }
    }

    // epilogue: C/D col = lane&15 (px), row = kg*4 + reg (o)
    float* ob = out + ((size_t)b * 1024 + i * 256) * 4096;
#pragma unroll
    for (int mi = 0; mi < 4; ++mi) {
        int o = wo * 64 + mi * 16 + kg * 4;
#pragma unroll
        for (int ni = 0; ni < 2; ++ni) {
            int pg = px0 + wp * 32 + ni * 16 + lm;
#pragma unroll
            for (int reg = 0; reg < 4; ++reg)
                ob[(size_t)(o + reg) * 4096 + pg] = acc[mi][ni][reg];
        }
    }
}

extern "C" void kernel_launch(void* const* d_in, const int* in_sizes, int n_in,
                              void* d_out, int out_size, void* d_ws, size_t ws_size,
                              hipStream_t stream) {
    const float* x  = (const float*)d_in[0];   // [2,256,64,64]
    const float* dw = (const float*)d_in[1];   // [4,256,256,3,3]
    const float* ow = (const float*)d_in[2];   // [4,18,256,3,3]
    const float* ob = (const float*)d_in[3];   // [4,18]
    float* out = (float*)d_out;                // [2,1024,64,64]

    float* ws  = (float*)d_ws;
    float* off = ws;                                        // 589824 f32
    __hip_bfloat16* wTb  = (__hip_bfloat16*)(ws + 589824);  // 2359296 bf16
    __hip_bfloat16* owTb = wTb + 2359296;                   // 294912 bf16
    unsigned short* x16  = (unsigned short*)(ws + 1916928); // 2097152 bf16

    convert_x_bf16<<<2048, 256, 0, stream>>>(x, x16);
    transpose_dw_bf16<<<9216, 256, 0, stream>>>(dw, wTb);
    transpose_ow_bf16<<<1152, 256, 0, stream>>>(ow, owTb);
    offset_mfma<<<256, 512, 0, stream>>>(x, owTb, ob, off);
    deform_mfma3<<<512, 512, 0, stream>>>(x16, wTb, off, out);
}

// Round 7
// 199.649 us; speedup vs baseline: 1.4737x; 1.4713x over previous
//
#include <hip/hip_runtime.h>
#include <hip/hip_bf16.h>

typedef __attribute__((ext_vector_type(8))) short bf16x8;
typedef __attribute__((ext_vector_type(4))) float f32x4;

__device__ __forceinline__ unsigned int rne_pack(float s0, float s1) {
    unsigned int b0 = __float_as_uint(s0), b1 = __float_as_uint(s1);
    b0 += 0x7fffu + ((b0 >> 16) & 1);
    b1 += 0x7fffu + ((b1 >> 16) & 1);
    return (b0 >> 16) | (b1 & 0xffff0000u);
}
__device__ __forceinline__ float ubf(unsigned short u) {
    return __uint_as_float(((unsigned int)u) << 16);
}

// ---------------- x -> bf16 copy (for deform gather) ----------------
__global__ __launch_bounds__(256) void convert_x_bf16(const float* __restrict__ x,
                                                      unsigned short* __restrict__ x16) {
    int idx = blockIdx.x * 256 + threadIdx.x;      // 524288 float4s
    float4 v = ((const float4*)x)[idx];
    unsigned int lo = rne_pack(v.x, v.y), hi = rne_pack(v.z, v.w);
    ((uint2*)x16)[idx] = make_uint2(lo, hi);
}

// ---------------- weight transposes ----------------
// dweights [4][256][256][3][3] fp32 -> wTb [i][k][o][c] bf16
__global__ __launch_bounds__(256) void transpose_dw_bf16(const float* __restrict__ dw,
                                                         __hip_bfloat16* __restrict__ wTb) {
    int idx = blockIdx.x * 256 + threadIdx.x;      // 2359296
    int c = idx & 255;
    int o = (idx >> 8) & 255;
    int rest = idx >> 16;                          // i*9 + k
    int k = rest % 9, i = rest / 9;
    wTb[idx] = __float2bfloat16(dw[(((i << 8) + o) * 256 + c) * 9 + k]);
}

// oweights [4][18][256][3][3] fp32 -> owTb [r][k][32][256] bf16 (rows 18..31 zero)
__global__ __launch_bounds__(256) void transpose_ow_bf16(const float* __restrict__ ow,
                                                         __hip_bfloat16* __restrict__ owTb) {
    int idx = blockIdx.x * 256 + threadIdx.x;      // 294912
    int c = idx & 255;
    int m = (idx >> 8) & 31;
    int rk = idx >> 13;
    int k = rk % 9, r = rk / 9;
    float v = (m < 18) ? ow[((r * 18 + m) * 256 + c) * 9 + k] : 0.f;
    owTb[idx] = __float2bfloat16(v);
}

// ---------------- offset conv as bf16-MFMA implicit GEMM (verified r4) ----------------
__global__ __launch_bounds__(512) void offset_mfma(const float* __restrict__ x,
                                                   const __hip_bfloat16* __restrict__ owTb,
                                                   const float* __restrict__ obias,
                                                   float* __restrict__ off) {
    __shared__ short s_a[4][32][8];
    __shared__ short s_b[4][128][8];
    __shared__ int   s_pix[9][128];
    __shared__ float s_msk[9][128];

    const int blk = blockIdx.x;
    const int r = (blk & 7) >> 1, b = blk & 1;
    const int px0 = (blk >> 3) << 7;
    const int rate = 6 * (r + 1);

    const int tid = threadIdx.x;
    const int lane = tid & 63;
    const int w = tid >> 6;
    const int kg = lane >> 4, lm = lane & 15;
    const int sg = tid >> 7, spx = tid & 127;
    const int mA = (tid & 127) >> 2, kgA = tid & 3;

    const float* xb = x + (size_t)b * 256 * 4096;
    const unsigned short* wrb = (const unsigned short*)owTb + (size_t)r * 9 * 32 * 256;

    for (int e = tid; e < 1152; e += 512) {
        int k = e >> 7, pl = e & 127;
        int pg = px0 + pl;
        int yy = (pg >> 6) + (k / 3 - 1) * rate;
        int xx = (pg & 63) + (k % 3 - 1) * rate;
        bool v = ((unsigned)yy < 64u) && ((unsigned)xx < 64u);
        int cy = min(max(yy, 0), 63), cx = min(max(xx, 0), 63);
        s_pix[k][pl] = cy * 64 + cx;
        s_msk[k][pl] = v ? 1.f : 0.f;
    }
    __syncthreads();

    f32x4 acc0 = (f32x4)(0.f), acc1 = (f32x4)(0.f);

    for (int t = 0; t < 72; ++t) {
        const int tap = t >> 3;
        const int c0 = (t & 7) << 5;

        uint4 a;
        if (tid < 128)
            a = *(const uint4*)(wrb + ((size_t)tap * 32 + mA) * 256 + c0 + kgA * 8);

        int pix = s_pix[tap][spx];
        float msk = s_msk[tap][spx];
        const float* xc = xb + (size_t)(c0 + sg * 8) * 4096;
        float sv[8];
#pragma unroll
        for (int j = 0; j < 8; ++j)
            sv[j] = xc[(size_t)j * 4096 + pix] * msk;
        uint4 pk = make_uint4(rne_pack(sv[0], sv[1]), rne_pack(sv[2], sv[3]),
                              rne_pack(sv[4], sv[5]), rne_pack(sv[6], sv[7]));

        __syncthreads();
        if (tid < 128) *(uint4*)&s_a[kgA][mA][0] = a;
        *(uint4*)&s_b[sg][spx][0] = pk;
        __syncthreads();

        bf16x8 bf  = *(const bf16x8*)&s_b[kg][w * 16 + lm][0];
        bf16x8 af0 = *(const bf16x8*)&s_a[kg][lm][0];
        bf16x8 af1 = *(const bf16x8*)&s_a[kg][16 + lm][0];
        acc0 = __builtin_amdgcn_mfma_f32_16x16x32_bf16(af0, bf, acc0, 0, 0, 0);
        acc1 = __builtin_amdgcn_mfma_f32_16x16x32_bf16(af1, bf, acc1, 0, 0, 0);
    }

    const float* bias = obias + r * 18;
    float* ob = off + (size_t)(r * 2 + b) * 18 * 4096;
    int px = px0 + w * 16 + lm;
#pragma unroll
    for (int reg = 0; reg < 4; ++reg) {
        int m = kg * 4 + reg;
        ob[(size_t)m * 4096 + px] = fmaxf(acc0[reg] + bias[m], 0.f);
        int m1 = 16 + m;
        if (m1 < 18)
            ob[(size_t)m1 * 4096 + px] = fmaxf(acc1[reg] + bias[m1], 0.f);
    }
}

// ---------------- deformable conv v4: named-scalar A staging (no scratch array) ----------------
// grid: 512 blocks; blk&7 = (i,b), blk>>3 = 64-px tile (one row). 512 threads = 8 waves.
// Tile: 256o x 64px, K-step 64 (tap x 64ch), 36 steps, 2 barriers/step.
// r5/r6 lesson: a uint4 a[4] staging ARRAY gets demoted to scratch regardless of
// VGPR budget (507 MB HBM write traffic). Named scalars (r4 pattern) stay in VGPRs.
__global__ __launch_bounds__(512, 2) void deform_mfma4(const unsigned short* __restrict__ x16,
                                                       const __hip_bfloat16* __restrict__ wTb,
                                                       const float* __restrict__ off,
                                                       float* __restrict__ out) {
    __shared__ short  s_a[256][64];     // [o][64 step-ch], col ^= (o&7)*8 swizzle  32 KB
    __shared__ short  s_b[8][64][8];    // [octet][px][8ch]                          8 KB
    __shared__ int4   s_pix[9][64];
    __shared__ float4 s_wt[9][64];

    const int blk = blockIdx.x;
    const int i = (blk & 7) >> 1, b = blk & 1;
    const int px0 = (blk >> 3) << 6;
    const int r = (i + 3) & 3;
    const int rate = 6 * (i + 1);

    const int tid = threadIdx.x;
    const int lane = tid & 63;
    const int w = tid >> 6;
    const int wo = w >> 1, wp = w & 1;          // o-quarter (64), px-half (32)
    const int kg = lane >> 4, lm = lane & 15;
    const int kgB = tid >> 6, pxB = tid & 63;   // B staging: octet, pixel
    const int oA = tid >> 3, partA = tid & 7;   // A staging: o-row, 16B part
    const int colA = (partA * 8) ^ ((oA & 7) * 8);  // same col for oA+64k

    const unsigned short* xb = x16 + (size_t)b * 1048576;
    const float* offb = off + (size_t)(r * 2 + b) * 18 * 4096;
    const unsigned short* wib = (const unsigned short*)wTb + (size_t)i * 9 * 65536;

    // bilinear coords/weights: 9 taps x 64 px
    for (int e = tid; e < 576; e += 512) {
        int k = e >> 6, pl = e & 63;
        int pg = px0 + pl;
        int yy = pg >> 6, xc = pg & 63;
        float dy = offb[(size_t)(2 * k) * 4096 + pg];
        float dx = offb[(size_t)(2 * k + 1) * 4096 + pg];
        float py = (float)(yy + (k / 3 - 1) * rate) + dy;
        float pxf = (float)(xc + (k % 3 - 1) * rate) + dx;
        float fy = floorf(py), fx = floorf(pxf);
        int y0 = (int)fy, x0 = (int)fx;
        float wy = py - fy, wx = pxf - fx;
        float vy0 = ((unsigned)y0 < 64u) ? 1.f : 0.f;
        float vy1 = ((unsigned)(y0 + 1) < 64u) ? 1.f : 0.f;
        float vx0 = ((unsigned)x0 < 64u) ? 1.f : 0.f;
        float vx1 = ((unsigned)(x0 + 1) < 64u) ? 1.f : 0.f;
        int cy0 = min(max(y0, 0), 63), cy1 = min(max(y0 + 1, 0), 63);
        int cx0 = min(max(x0, 0), 63), cx1 = min(max(x0 + 1, 0), 63);
        s_pix[k][pl] = make_int4(cy0 * 64 + cx0, cy0 * 64 + cx1,
                                 cy1 * 64 + cx0, cy1 * 64 + cx1);
        s_wt[k][pl] = make_float4(vy0 * vx0 * (1.f - wy) * (1.f - wx),
                                  vy0 * vx1 * (1.f - wy) * wx,
                                  vy1 * vx0 * wy * (1.f - wx),
                                  vy1 * vx1 * wy * wx);
    }
    __syncthreads();

    f32x4 acc[4][2];
#pragma unroll
    for (int mi = 0; mi < 4; ++mi) {
        acc[mi][0] = (f32x4)(0.f);
        acc[mi][1] = (f32x4)(0.f);
    }

    for (int t = 0; t < 36; ++t) {
        const int tap = t >> 2;
        const int c0 = (t & 3) << 6;

        // -- A: 4 coalesced uint4 loads, NAMED scalars (8 lanes = contiguous 128 B) --
        const unsigned short* wrow = wib + (size_t)tap * 65536 + c0 + partA * 8;
        uint4 a0 = *(const uint4*)(wrow + (size_t)(oA      ) * 256);
        uint4 a1 = *(const uint4*)(wrow + (size_t)(oA +  64) * 256);
        uint4 a2 = *(const uint4*)(wrow + (size_t)(oA + 128) * 256);
        uint4 a3 = *(const uint4*)(wrow + (size_t)(oA + 192) * 256);

        // -- B: bilinear gather of 8 channels from bf16 x --
        int4 p = s_pix[tap][pxB];
        float4 qw = s_wt[tap][pxB];
        const unsigned short* xc = xb + (size_t)(c0 + kgB * 8) * 4096;
        unsigned int pk0, pk1, pk2, pk3;
        {
            float s0, s1;
            const unsigned short* q0 = xc;
            s0 = ubf(q0[p.x]) * qw.x + ubf(q0[p.y]) * qw.y + ubf(q0[p.z]) * qw.z + ubf(q0[p.w]) * qw.w;
            const unsigned short* q1 = xc + 4096;
            s1 = ubf(q1[p.x]) * qw.x + ubf(q1[p.y]) * qw.y + ubf(q1[p.z]) * qw.z + ubf(q1[p.w]) * qw.w;
            pk0 = rne_pack(s0, s1);
            const unsigned short* q2 = xc + 2 * 4096;
            s0 = ubf(q2[p.x]) * qw.x + ubf(q2[p.y]) * qw.y + ubf(q2[p.z]) * qw.z + ubf(q2[p.w]) * qw.w;
            const unsigned short* q3 = xc + 3 * 4096;
            s1 = ubf(q3[p.x]) * qw.x + ubf(q3[p.y]) * qw.y + ubf(q3[p.z]) * qw.z + ubf(q3[p.w]) * qw.w;
            pk1 = rne_pack(s0, s1);
            const unsigned short* q4 = xc + 4 * 4096;
            s0 = ubf(q4[p.x]) * qw.x + ubf(q4[p.y]) * qw.y + ubf(q4[p.z]) * qw.z + ubf(q4[p.w]) * qw.w;
            const unsigned short* q5 = xc + 5 * 4096;
            s1 = ubf(q5[p.x]) * qw.x + ubf(q5[p.y]) * qw.y + ubf(q5[p.z]) * qw.z + ubf(q5[p.w]) * qw.w;
            pk2 = rne_pack(s0, s1);
            const unsigned short* q6 = xc + 6 * 4096;
            s0 = ubf(q6[p.x]) * qw.x + ubf(q6[p.y]) * qw.y + ubf(q6[p.z]) * qw.z + ubf(q6[p.w]) * qw.w;
            const unsigned short* q7 = xc + 7 * 4096;
            s1 = ubf(q7[p.x]) * qw.x + ubf(q7[p.y]) * qw.y + ubf(q7[p.z]) * qw.z + ubf(q7[p.w]) * qw.w;
            pk3 = rne_pack(s0, s1);
        }

        __syncthreads();
        *(uint4*)&s_a[oA      ][colA] = a0;
        *(uint4*)&s_a[oA +  64][colA] = a1;
        *(uint4*)&s_a[oA + 128][colA] = a2;
        *(uint4*)&s_a[oA + 192][colA] = a3;
        *(uint2*)&s_b[kgB][pxB][0] = make_uint2(pk0, pk1);
        *(uint2*)&s_b[kgB][pxB][4] = make_uint2(pk2, pk3);
        __syncthreads();

#pragma unroll
        for (int kf = 0; kf < 2; ++kf) {
            int oct = kf * 4 + kg;
            bf16x8 bf0 = *(const bf16x8*)&s_b[oct][wp * 32 + lm][0];
            bf16x8 bf1 = *(const bf16x8*)&s_b[oct][wp * 32 + 16 + lm][0];
#pragma unroll
            for (int mi = 0; mi < 4; ++mi) {
                int o = wo * 64 + mi * 16 + lm;
                int col = (oct * 8) ^ ((o & 7) * 8);
                bf16x8 af = *(const bf16x8*)&s_a[o][col];
                acc[mi][0] = __builtin_amdgcn_mfma_f32_16x16x32_bf16(af, bf0, acc[mi][0], 0, 0, 0);
                acc[mi][1] = __builtin_amdgcn_mfma_f32_16x16x32_bf16(af, bf1, acc[mi][1], 0, 0, 0);
            }
        }
    }

    // epilogue: C/D col = lane&15 (px), row = kg*4 + reg (o)
    float* ob = out + ((size_t)b * 1024 + i * 256) * 4096;
#pragma unroll
    for (int mi = 0; mi < 4; ++mi) {
        int o = wo * 64 + mi * 16 + kg * 4;
#pragma unroll
        for (int ni = 0; ni < 2; ++ni) {
            int pg = px0 + wp * 32 + ni * 16 + lm;
#pragma unroll
            for (int reg = 0; reg < 4; ++reg)
                ob[(size_t)(o + reg) * 4096 + pg] = acc[mi][ni][reg];
        }
    }
}

extern "C" void kernel_launch(void* const* d_in, const int* in_sizes, int n_in,
                              void* d_out, int out_size, void* d_ws, size_t ws_size,
                              hipStream_t stream) {
    const float* x  = (const float*)d_in[0];   // [2,256,64,64]
    const float* dw = (const float*)d_in[1];   // [4,256,256,3,3]
    const float* ow = (const float*)d_in[2];   // [4,18,256,3,3]
    const float* ob = (const float*)d_in[3];   // [4,18]
    float* out = (float*)d_out;                // [2,1024,64,64]

    float* ws  = (float*)d_ws;
    float* off = ws;                                        // 589824 f32
    __hip_bfloat16* wTb  = (__hip_bfloat16*)(ws + 589824);  // 2359296 bf16
    __hip_bfloat16* owTb = wTb + 2359296;                   // 294912 bf16
    unsigned short* x16  = (unsigned short*)(ws + 1916928); // 2097152 bf16

    convert_x_bf16<<<2048, 256, 0, stream>>>(x, x16);
    transpose_dw_bf16<<<9216, 256, 0, stream>>>(dw, wTb);
    transpose_ow_bf16<<<1152, 256, 0, stream>>>(ow, owTb);
    offset_mfma<<<256, 512, 0, stream>>>(x, owTb, ob, off);
    deform_mfma4<<<512, 512, 0, stream>>>(x16, wTb, off, out);
}

// Round 8
// 120.859 us; speedup vs baseline: 2.4344x; 1.6519x over previous
//
#include <hip/hip_runtime.h>
#include <hip/hip_bf16.h>

typedef __attribute__((ext_vector_type(8))) short bf16x8;
typedef __attribute__((ext_vector_type(4))) float f32x4;

__device__ __forceinline__ unsigned int rne_pack(float s0, float s1) {
    unsigned int b0 = __float_as_uint(s0), b1 = __float_as_uint(s1);
    b0 += 0x7fffu + ((b0 >> 16) & 1);
    b1 += 0x7fffu + ((b1 >> 16) & 1);
    return (b0 >> 16) | (b1 & 0xffff0000u);
}

// ---------------- x [2][256][4096] f32 -> x16h [2][4096][256] bf16 (HWC) ----------------
__global__ __launch_bounds__(256) void transpose_x_hwc(const float* __restrict__ x,
                                                       unsigned short* __restrict__ x16h) {
    __shared__ float s[64][65];
    int blk = blockIdx.x;                 // 2 b * 4 ct * 64 pt = 512
    int b = blk >> 8, ct = (blk >> 6) & 3, pt = blk & 63;
    int c0 = ct * 64, p0 = pt * 64;
    int tid = threadIdx.x;
    int tr = tid >> 6, tc = tid & 63;     // 4 x 64
#pragma unroll
    for (int i = 0; i < 16; ++i) {
        int c = i * 4 + tr;
        s[c][tc] = x[((size_t)b * 256 + c0 + c) * 4096 + p0 + tc];
    }
    __syncthreads();
#pragma unroll
    for (int i = 0; i < 16; ++i) {
        int pp = i * 4 + tr;
        unsigned u = __float_as_uint(s[tc][pp]);
        u += 0x7fffu + ((u >> 16) & 1);
        x16h[((size_t)b * 4096 + p0 + pp) * 256 + c0 + tc] = (unsigned short)(u >> 16);
    }
}

// ---------------- weight transposes ----------------
// dweights [4][256][256][3][3] fp32 -> wTb [i][k][o][c] bf16
__global__ __launch_bounds__(256) void transpose_dw_bf16(const float* __restrict__ dw,
                                                         __hip_bfloat16* __restrict__ wTb) {
    int idx = blockIdx.x * 256 + threadIdx.x;      // 2359296
    int c = idx & 255;
    int o = (idx >> 8) & 255;
    int rest = idx >> 16;                          // i*9 + k
    int k = rest % 9, i = rest / 9;
    wTb[idx] = __float2bfloat16(dw[(((i << 8) + o) * 256 + c) * 9 + k]);
}

// oweights [4][18][256][3][3] fp32 -> owTb [r][k][32][256] bf16 (rows 18..31 zero)
__global__ __launch_bounds__(256) void transpose_ow_bf16(const float* __restrict__ ow,
                                                         __hip_bfloat16* __restrict__ owTb) {
    int idx = blockIdx.x * 256 + threadIdx.x;      // 294912
    int c = idx & 255;
    int m = (idx >> 8) & 31;
    int rk = idx >> 13;
    int k = rk % 9, r = rk / 9;
    float v = (m < 18) ? ow[((r * 18 + m) * 256 + c) * 9 + k] : 0.f;
    owTb[idx] = __float2bfloat16(v);
}

// ---------------- offset conv as bf16-MFMA implicit GEMM (verified r4, unchanged) ----------------
__global__ __launch_bounds__(512) void offset_mfma(const float* __restrict__ x,
                                                   const __hip_bfloat16* __restrict__ owTb,
                                                   const float* __restrict__ obias,
                                                   float* __restrict__ off) {
    __shared__ short s_a[4][32][8];
    __shared__ short s_b[4][128][8];
    __shared__ int   s_pix[9][128];
    __shared__ float s_msk[9][128];

    const int blk = blockIdx.x;
    const int r = (blk & 7) >> 1, b = blk & 1;
    const int px0 = (blk >> 3) << 7;
    const int rate = 6 * (r + 1);

    const int tid = threadIdx.x;
    const int lane = tid & 63;
    const int w = tid >> 6;
    const int kg = lane >> 4, lm = lane & 15;
    const int sg = tid >> 7, spx = tid & 127;
    const int mA = (tid & 127) >> 2, kgA = tid & 3;

    const float* xb = x + (size_t)b * 256 * 4096;
    const unsigned short* wrb = (const unsigned short*)owTb + (size_t)r * 9 * 32 * 256;

    for (int e = tid; e < 1152; e += 512) {
        int k = e >> 7, pl = e & 127;
        int pg = px0 + pl;
        int yy = (pg >> 6) + (k / 3 - 1) * rate;
        int xx = (pg & 63) + (k % 3 - 1) * rate;
        bool v = ((unsigned)yy < 64u) && ((unsigned)xx < 64u);
        int cy = min(max(yy, 0), 63), cx = min(max(xx, 0), 63);
        s_pix[k][pl] = cy * 64 + cx;
        s_msk[k][pl] = v ? 1.f : 0.f;
    }
    __syncthreads();

    f32x4 acc0 = (f32x4)(0.f), acc1 = (f32x4)(0.f);

    for (int t = 0; t < 72; ++t) {
        const int tap = t >> 3;
        const int c0 = (t & 7) << 5;

        uint4 a;
        if (tid < 128)
            a = *(const uint4*)(wrb + ((size_t)tap * 32 + mA) * 256 + c0 + kgA * 8);

        int pix = s_pix[tap][spx];
        float msk = s_msk[tap][spx];
        const float* xc = xb + (size_t)(c0 + sg * 8) * 4096;
        float sv[8];
#pragma unroll
        for (int j = 0; j < 8; ++j)
            sv[j] = xc[(size_t)j * 4096 + pix] * msk;
        uint4 pk = make_uint4(rne_pack(sv[0], sv[1]), rne_pack(sv[2], sv[3]),
                              rne_pack(sv[4], sv[5]), rne_pack(sv[6], sv[7]));

        __syncthreads();
        if (tid < 128) *(uint4*)&s_a[kgA][mA][0] = a;
        *(uint4*)&s_b[sg][spx][0] = pk;
        __syncthreads();

        bf16x8 bf  = *(const bf16x8*)&s_b[kg][w * 16 + lm][0];
        bf16x8 af0 = *(const bf16x8*)&s_a[kg][lm][0];
        bf16x8 af1 = *(const bf16x8*)&s_a[kg][16 + lm][0];
        acc0 = __builtin_amdgcn_mfma_f32_16x16x32_bf16(af0, bf, acc0, 0, 0, 0);
        acc1 = __builtin_amdgcn_mfma_f32_16x16x32_bf16(af1, bf, acc1, 0, 0, 0);
    }

    const float* bias = obias + r * 18;
    float* ob = off + (size_t)(r * 2 + b) * 18 * 4096;
    int px = px0 + w * 16 + lm;
#pragma unroll
    for (int reg = 0; reg < 4; ++reg) {
        int m = kg * 4 + reg;
        ob[(size_t)m * 4096 + px] = fmaxf(acc0[reg] + bias[m], 0.f);
        int m1 = 16 + m;
        if (m1 < 18)
            ob[(size_t)m1 * 4096 + px] = fmaxf(acc1[reg] + bias[m1], 0.f);
    }
}

// ---------------- deformable conv v5: HWC dense gather ----------------
// grid: 512 blocks; blk&7 = (i,b), blk>>3 = 64-px tile (one row). 512 threads = 8 waves.
// Tile: 256o x 64px, K-step 64 (tap x 64ch), 36 steps, 2 barriers/step.
// B staging: thread = (px=tid>>3, chg=tid&7); 4 corner loads are dwordx4 of 8
// CONTIGUOUS channels (HWC layout) -> 4 dense VMEM instrs vs 32 scattered (r7).
// s_b XOR swizzle col = chg ^ (px&7) on both write and read.
#define LERPW(W) rne_pack(                                                      \
    __uint_as_float(v0.W << 16) * qx + __uint_as_float(v1.W << 16) * qy +       \
    __uint_as_float(v2.W << 16) * qz + __uint_as_float(v3.W << 16) * qv,        \
    __uint_as_float(v0.W & 0xffff0000u) * qx + __uint_as_float(v1.W & 0xffff0000u) * qy + \
    __uint_as_float(v2.W & 0xffff0000u) * qz + __uint_as_float(v3.W & 0xffff0000u) * qv)

__global__ __launch_bounds__(512, 2) void deform_mfma5(const unsigned short* __restrict__ x16h,
                                                       const __hip_bfloat16* __restrict__ wTb,
                                                       const float* __restrict__ off,
                                                       float* __restrict__ out) {
    __shared__ short  s_a[256][64];     // [o][64 step-ch], col ^= (o&7)*8 swizzle  32 KB
    __shared__ short  s_b[64][64];      // [px][oct^(px&7) octets of 8ch]            8 KB
    __shared__ int4   s_pix[9][64];
    __shared__ float4 s_wt[9][64];

    const int blk = blockIdx.x;
    const int i = (blk & 7) >> 1, b = blk & 1;
    const int px0 = (blk >> 3) << 6;
    const int r = (i + 3) & 3;
    const int rate = 6 * (i + 1);

    const int tid = threadIdx.x;
    const int lane = tid & 63;
    const int w = tid >> 6;
    const int wo = w >> 1, wp = w & 1;          // o-quarter (64), px-half (32)
    const int kg = lane >> 4, lm = lane & 15;
    const int pxS = tid >> 3, chgS = tid & 7;   // B staging: pixel, channel-octet
    const int oA = tid >> 3, partA = tid & 7;   // A staging: o-row, 16B part
    const int colA = (partA * 8) ^ ((oA & 7) * 8);

    const unsigned short* xbh = x16h + (size_t)b * 1048576;   // [pix][256ch]
    const float* offb = off + (size_t)(r * 2 + b) * 18 * 4096;
    const unsigned short* wib = (const unsigned short*)wTb + (size_t)i * 9 * 65536;

    // bilinear coords/weights: 9 taps x 64 px (validity folded into weights)
    for (int e = tid; e < 576; e += 512) {
        int k = e >> 6, pl = e & 63;
        int pg = px0 + pl;
        int yy = pg >> 6, xc = pg & 63;
        float dy = offb[(size_t)(2 * k) * 4096 + pg];
        float dx = offb[(size_t)(2 * k + 1) * 4096 + pg];
        float py = (float)(yy + (k / 3 - 1) * rate) + dy;
        float pxf = (float)(xc + (k % 3 - 1) * rate) + dx;
        float fy = floorf(py), fx = floorf(pxf);
        int y0 = (int)fy, x0 = (int)fx;
        float wy = py - fy, wx = pxf - fx;
        float vy0 = ((unsigned)y0 < 64u) ? 1.f : 0.f;
        float vy1 = ((unsigned)(y0 + 1) < 64u) ? 1.f : 0.f;
        float vx0 = ((unsigned)x0 < 64u) ? 1.f : 0.f;
        float vx1 = ((unsigned)(x0 + 1) < 64u) ? 1.f : 0.f;
        int cy0 = min(max(y0, 0), 63), cy1 = min(max(y0 + 1, 0), 63);
        int cx0 = min(max(x0, 0), 63), cx1 = min(max(x0 + 1, 0), 63);
        s_pix[k][pl] = make_int4(cy0 * 64 + cx0, cy0 * 64 + cx1,
                                 cy1 * 64 + cx0, cy1 * 64 + cx1);
        s_wt[k][pl] = make_float4(vy0 * vx0 * (1.f - wy) * (1.f - wx),
                                  vy0 * vx1 * (1.f - wy) * wx,
                                  vy1 * vx0 * wy * (1.f - wx),
                                  vy1 * vx1 * wy * wx);
    }
    __syncthreads();

    f32x4 acc[4][2];
#pragma unroll
    for (int mi = 0; mi < 4; ++mi) {
        acc[mi][0] = (f32x4)(0.f);
        acc[mi][1] = (f32x4)(0.f);
    }

    for (int t = 0; t < 36; ++t) {
        const int tap = t >> 2;
        const int c0 = (t & 3) << 6;

        // -- A: 4 coalesced uint4 loads, named scalars (r7-verified pattern) --
        const unsigned short* wrow = wib + (size_t)tap * 65536 + c0 + partA * 8;
        uint4 a0 = *(const uint4*)(wrow + (size_t)(oA      ) * 256);
        uint4 a1 = *(const uint4*)(wrow + (size_t)(oA +  64) * 256);
        uint4 a2 = *(const uint4*)(wrow + (size_t)(oA + 128) * 256);
        uint4 a3 = *(const uint4*)(wrow + (size_t)(oA + 192) * 256);

        // -- B: 4 dense corner loads (8 contiguous channels each), lerp, pack --
        int4 p = s_pix[tap][pxS];
        float4 qw = s_wt[tap][pxS];
        float qx = qw.x, qy = qw.y, qz = qw.z, qv = qw.w;
        const unsigned short* xch = xbh + c0 + chgS * 8;
        uint4 v0 = *(const uint4*)(xch + ((size_t)p.x << 8));
        uint4 v1 = *(const uint4*)(xch + ((size_t)p.y << 8));
        uint4 v2 = *(const uint4*)(xch + ((size_t)p.z << 8));
        uint4 v3 = *(const uint4*)(xch + ((size_t)p.w << 8));
        unsigned pk0 = LERPW(x), pk1 = LERPW(y), pk2 = LERPW(z), pk3 = LERPW(w);

        __syncthreads();
        *(uint4*)&s_a[oA      ][colA] = a0;
        *(uint4*)&s_a[oA +  64][colA] = a1;
        *(uint4*)&s_a[oA + 128][colA] = a2;
        *(uint4*)&s_a[oA + 192][colA] = a3;
        *(uint4*)&s_b[pxS][(chgS ^ (pxS & 7)) * 8] = make_uint4(pk0, pk1, pk2, pk3);
        __syncthreads();

#pragma unroll
        for (int kf = 0; kf < 2; ++kf) {
            int oct = kf * 4 + kg;
            int bcol = (oct ^ (lm & 7)) * 8;
            bf16x8 bf0 = *(const bf16x8*)&s_b[wp * 32 + lm][bcol];
            bf16x8 bf1 = *(const bf16x8*)&s_b[wp * 32 + 16 + lm][bcol];
#pragma unroll
            for (int mi = 0; mi < 4; ++mi) {
                int o = wo * 64 + mi * 16 + lm;
                int col = (oct * 8) ^ ((o & 7) * 8);
                bf16x8 af = *(const bf16x8*)&s_a[o][col];
                acc[mi][0] = __builtin_amdgcn_mfma_f32_16x16x32_bf16(af, bf0, acc[mi][0], 0, 0, 0);
                acc[mi][1] = __builtin_amdgcn_mfma_f32_16x16x32_bf16(af, bf1, acc[mi][1], 0, 0, 0);
            }
        }
    }

    // epilogue: C/D col = lane&15 (px), row = kg*4 + reg (o)
    float* ob = out + ((size_t)b * 1024 + i * 256) * 4096;
#pragma unroll
    for (int mi = 0; mi < 4; ++mi) {
        int o = wo * 64 + mi * 16 + kg * 4;
#pragma unroll
        for (int ni = 0; ni < 2; ++ni) {
            int pg = px0 + wp * 32 + ni * 16 + lm;
#pragma unroll
            for (int reg = 0; reg < 4; ++reg)
                ob[(size_t)(o + reg) * 4096 + pg] = acc[mi][ni][reg];
        }
    }
}

extern "C" void kernel_launch(void* const* d_in, const int* in_sizes, int n_in,
                              void* d_out, int out_size, void* d_ws, size_t ws_size,
                              hipStream_t stream) {
    const float* x  = (const float*)d_in[0];   // [2,256,64,64]
    const float* dw = (const float*)d_in[1];   // [4,256,256,3,3]
    const float* ow = (const float*)d_in[2];   // [4,18,256,3,3]
    const float* ob = (const float*)d_in[3];   // [4,18]
    float* out = (float*)d_out;                // [2,1024,64,64]

    float* ws  = (float*)d_ws;
    float* off = ws;                                        // 589824 f32
    __hip_bfloat16* wTb  = (__hip_bfloat16*)(ws + 589824);  // 2359296 bf16
    __hip_bfloat16* owTb = wTb + 2359296;                   // 294912 bf16
    unsigned short* x16h = (unsigned short*)(ws + 1916928); // 2097152 bf16 [b][pix][c]

    transpose_x_hwc<<<512, 256, 0, stream>>>(x, x16h);
    transpose_dw_bf16<<<9216, 256, 0, stream>>>(dw, wTb);
    transpose_ow_bf16<<<1152, 256, 0, stream>>>(ow, owTb);
    offset_mfma<<<256, 512, 0, stream>>>(x, owTb, ob, off);
    deform_mfma5<<<512, 512, 0, stream>>>(x16h, wTb, off, out);
}

// Round 9
// 119.131 us; speedup vs baseline: 2.4697x; 1.0145x over previous
//
#include <hip/hip_runtime.h>
#include <hip/hip_bf16.h>

typedef __attribute__((ext_vector_type(8))) short bf16x8;
typedef __attribute__((ext_vector_type(4))) float f32x4;
typedef __attribute__((ext_vector_type(2))) _Float16 h2;
typedef __attribute__((ext_vector_type(8))) _Float16 f16x8;

__device__ __forceinline__ unsigned int rne_pack(float s0, float s1) {
    unsigned int b0 = __float_as_uint(s0), b1 = __float_as_uint(s1);
    b0 += 0x7fffu + ((b0 >> 16) & 1);
    b1 += 0x7fffu + ((b1 >> 16) & 1);
    return (b0 >> 16) | (b1 & 0xffff0000u);
}

// ---------------- x [2][256][4096] f32 -> x16h [2][4096][256] f16 (HWC) ----------------
__global__ __launch_bounds__(256) void transpose_x_hwc_f16(const float* __restrict__ x,
                                                           unsigned short* __restrict__ x16h) {
    __shared__ float s[64][65];
    int blk = blockIdx.x;                 // 2 b * 4 ct * 64 pt = 512
    int b = blk >> 8, ct = (blk >> 6) & 3, pt = blk & 63;
    int c0 = ct * 64, p0 = pt * 64;
    int tid = threadIdx.x;
    int tr = tid >> 6, tc = tid & 63;     // 4 x 64
#pragma unroll
    for (int i = 0; i < 16; ++i) {
        int c = i * 4 + tr;
        s[c][tc] = x[((size_t)b * 256 + c0 + c) * 4096 + p0 + tc];
    }
    __syncthreads();
#pragma unroll
    for (int i = 0; i < 16; ++i) {
        int pp = i * 4 + tr;
        _Float16 h = (_Float16)s[tc][pp];
        x16h[((size_t)b * 4096 + p0 + pp) * 256 + c0 + tc] = *(unsigned short*)&h;
    }
}

// ---------------- weight transposes ----------------
// dweights [4][256][256][3][3] fp32 -> wTh [i][k][o][c] f16
__global__ __launch_bounds__(256) void transpose_dw_f16(const float* __restrict__ dw,
                                                        unsigned short* __restrict__ wTh) {
    int idx = blockIdx.x * 256 + threadIdx.x;      // 2359296
    int c = idx & 255;
    int o = (idx >> 8) & 255;
    int rest = idx >> 16;                          // i*9 + k
    int k = rest % 9, i = rest / 9;
    _Float16 h = (_Float16)dw[(((i << 8) + o) * 256 + c) * 9 + k];
    wTh[idx] = *(unsigned short*)&h;
}

// oweights [4][18][256][3][3] fp32 -> owTb [r][k][32][256] bf16 (rows 18..31 zero)
__global__ __launch_bounds__(256) void transpose_ow_bf16(const float* __restrict__ ow,
                                                         __hip_bfloat16* __restrict__ owTb) {
    int idx = blockIdx.x * 256 + threadIdx.x;      // 294912
    int c = idx & 255;
    int m = (idx >> 8) & 31;
    int rk = idx >> 13;
    int k = rk % 9, r = rk / 9;
    float v = (m < 18) ? ow[((r * 18 + m) * 256 + c) * 9 + k] : 0.f;
    owTb[idx] = __float2bfloat16(v);
}

// ---------------- offset conv as bf16-MFMA implicit GEMM (verified r4, unchanged) ----------------
__global__ __launch_bounds__(512) void offset_mfma(const float* __restrict__ x,
                                                   const __hip_bfloat16* __restrict__ owTb,
                                                   const float* __restrict__ obias,
                                                   float* __restrict__ off) {
    __shared__ short s_a[4][32][8];
    __shared__ short s_b[4][128][8];
    __shared__ int   s_pix[9][128];
    __shared__ float s_msk[9][128];

    const int blk = blockIdx.x;
    const int r = (blk & 7) >> 1, b = blk & 1;
    const int px0 = (blk >> 3) << 7;
    const int rate = 6 * (r + 1);

    const int tid = threadIdx.x;
    const int lane = tid & 63;
    const int w = tid >> 6;
    const int kg = lane >> 4, lm = lane & 15;
    const int sg = tid >> 7, spx = tid & 127;
    const int mA = (tid & 127) >> 2, kgA = tid & 3;

    const float* xb = x + (size_t)b * 256 * 4096;
    const unsigned short* wrb = (const unsigned short*)owTb + (size_t)r * 9 * 32 * 256;

    for (int e = tid; e < 1152; e += 512) {
        int k = e >> 7, pl = e & 127;
        int pg = px0 + pl;
        int yy = (pg >> 6) + (k / 3 - 1) * rate;
        int xx = (pg & 63) + (k % 3 - 1) * rate;
        bool v = ((unsigned)yy < 64u) && ((unsigned)xx < 64u);
        int cy = min(max(yy, 0), 63), cx = min(max(xx, 0), 63);
        s_pix[k][pl] = cy * 64 + cx;
        s_msk[k][pl] = v ? 1.f : 0.f;
    }
    __syncthreads();

    f32x4 acc0 = (f32x4)(0.f), acc1 = (f32x4)(0.f);

    for (int t = 0; t < 72; ++t) {
        const int tap = t >> 3;
        const int c0 = (t & 7) << 5;

        uint4 a;
        if (tid < 128)
            a = *(const uint4*)(wrb + ((size_t)tap * 32 + mA) * 256 + c0 + kgA * 8);

        int pix = s_pix[tap][spx];
        float msk = s_msk[tap][spx];
        const float* xc = xb + (size_t)(c0 + sg * 8) * 4096;
        float sv[8];
#pragma unroll
        for (int j = 0; j < 8; ++j)
            sv[j] = xc[(size_t)j * 4096 + pix] * msk;
        uint4 pk = make_uint4(rne_pack(sv[0], sv[1]), rne_pack(sv[2], sv[3]),
                              rne_pack(sv[4], sv[5]), rne_pack(sv[6], sv[7]));

        __syncthreads();
        if (tid < 128) *(uint4*)&s_a[kgA][mA][0] = a;
        *(uint4*)&s_b[sg][spx][0] = pk;
        __syncthreads();

        bf16x8 bf  = *(const bf16x8*)&s_b[kg][w * 16 + lm][0];
        bf16x8 af0 = *(const bf16x8*)&s_a[kg][lm][0];
        bf16x8 af1 = *(const bf16x8*)&s_a[kg][16 + lm][0];
        acc0 = __builtin_amdgcn_mfma_f32_16x16x32_bf16(af0, bf, acc0, 0, 0, 0);
        acc1 = __builtin_amdgcn_mfma_f32_16x16x32_bf16(af1, bf, acc1, 0, 0, 0);
    }

    const float* bias = obias + r * 18;
    float* ob = off + (size_t)(r * 2 + b) * 18 * 4096;
    int px = px0 + w * 16 + lm;
#pragma unroll
    for (int reg = 0; reg < 4; ++reg) {
        int m = kg * 4 + reg;
        ob[(size_t)m * 4096 + px] = fmaxf(acc0[reg] + bias[m], 0.f);
        int m1 = 16 + m;
        if (m1 < 18)
            ob[(size_t)m1 * 4096 + px] = fmaxf(acc1[reg] + bias[m1], 0.f);
    }
}

// ---------------- deformable conv v6: HWC dense gather + packed-f16 lerp + f16 MFMA ----------------
// grid: 512 blocks; blk&7 = (i,b), blk>>3 = 64-px tile. 512 threads = 8 waves.
// Tile: 256o x 64px, K-step 64 (tap x 64ch), 36 steps, 2 barriers/step.
// r8 lesson: fp32 lerp+pack = ~88 VALU ops/thread/step was the limiter (VALUBusy 43%).
// f16 path: 4 corner words lerped with v_pk_fma_f16 (4 ops/word), result IS the fragment.
__global__ __launch_bounds__(512, 2) void deform_mfma6(const unsigned short* __restrict__ x16h,
                                                       const unsigned short* __restrict__ wTh,
                                                       const float* __restrict__ off,
                                                       float* __restrict__ out) {
    __shared__ short  s_a[256][64];     // [o][64 step-ch], col ^= (o&7)*8 swizzle  32 KB
    __shared__ short  s_b[64][64];      // [px][oct^(px&7) octets of 8ch]            8 KB
    __shared__ int4   s_pix[9][64];
    __shared__ float4 s_wt[9][64];

    const int blk = blockIdx.x;
    const int i = (blk & 7) >> 1, b = blk & 1;
    const int px0 = (blk >> 3) << 6;
    const int r = (i + 3) & 3;
    const int rate = 6 * (i + 1);

    const int tid = threadIdx.x;
    const int lane = tid & 63;
    const int w = tid >> 6;
    const int wo = w >> 1, wp = w & 1;          // o-quarter (64), px-half (32)
    const int kg = lane >> 4, lm = lane & 15;
    const int pxS = tid >> 3, chgS = tid & 7;   // B staging: pixel, channel-octet
    const int oA = tid >> 3, partA = tid & 7;   // A staging: o-row, 16B part
    const int colA = (partA * 8) ^ ((oA & 7) * 8);

    const unsigned short* xbh = x16h + (size_t)b * 1048576;   // [pix][256ch] f16
    const float* offb = off + (size_t)(r * 2 + b) * 18 * 4096;
    const unsigned short* wib = wTh + (size_t)i * 9 * 65536;

    // bilinear coords/weights: 9 taps x 64 px (validity folded into weights)
    for (int e = tid; e < 576; e += 512) {
        int k = e >> 6, pl = e & 63;
        int pg = px0 + pl;
        int yy = pg >> 6, xc = pg & 63;
        float dy = offb[(size_t)(2 * k) * 4096 + pg];
        float dx = offb[(size_t)(2 * k + 1) * 4096 + pg];
        float py = (float)(yy + (k / 3 - 1) * rate) + dy;
        float pxf = (float)(xc + (k % 3 - 1) * rate) + dx;
        float fy = floorf(py), fx = floorf(pxf);
        int y0 = (int)fy, x0 = (int)fx;
        float wy = py - fy, wx = pxf - fx;
        float vy0 = ((unsigned)y0 < 64u) ? 1.f : 0.f;
        float vy1 = ((unsigned)(y0 + 1) < 64u) ? 1.f : 0.f;
        float vx0 = ((unsigned)x0 < 64u) ? 1.f : 0.f;
        float vx1 = ((unsigned)(x0 + 1) < 64u) ? 1.f : 0.f;
        int cy0 = min(max(y0, 0), 63), cy1 = min(max(y0 + 1, 0), 63);
        int cx0 = min(max(x0, 0), 63), cx1 = min(max(x0 + 1, 0), 63);
        s_pix[k][pl] = make_int4(cy0 * 64 + cx0, cy0 * 64 + cx1,
                                 cy1 * 64 + cx0, cy1 * 64 + cx1);
        s_wt[k][pl] = make_float4(vy0 * vx0 * (1.f - wy) * (1.f - wx),
                                  vy0 * vx1 * (1.f - wy) * wx,
                                  vy1 * vx0 * wy * (1.f - wx),
                                  vy1 * vx1 * wy * wx);
    }
    __syncthreads();

    f32x4 acc[4][2];
#pragma unroll
    for (int mi = 0; mi < 4; ++mi) {
        acc[mi][0] = (f32x4)(0.f);
        acc[mi][1] = (f32x4)(0.f);
    }

    for (int t = 0; t < 36; ++t) {
        const int tap = t >> 2;
        const int c0 = (t & 3) << 6;

        // -- A: 4 coalesced uint4 loads, named scalars (r7-verified pattern) --
        const unsigned short* wrow = wib + (size_t)tap * 65536 + c0 + partA * 8;
        uint4 a0 = *(const uint4*)(wrow + (size_t)(oA      ) * 256);
        uint4 a1 = *(const uint4*)(wrow + (size_t)(oA +  64) * 256);
        uint4 a2 = *(const uint4*)(wrow + (size_t)(oA + 128) * 256);
        uint4 a3 = *(const uint4*)(wrow + (size_t)(oA + 192) * 256);

        // -- B: 4 dense corner loads (8 contiguous f16 channels), packed-f16 lerp --
        int4 p = s_pix[tap][pxS];
        float4 qwf = s_wt[tap][pxS];
        h2 qx = (h2)((_Float16)qwf.x), qy = (h2)((_Float16)qwf.y);
        h2 qz = (h2)((_Float16)qwf.z), qv = (h2)((_Float16)qwf.w);
        const unsigned short* xch = xbh + c0 + chgS * 8;
        uint4 v0 = *(const uint4*)(xch + ((size_t)p.x << 8));
        uint4 v1 = *(const uint4*)(xch + ((size_t)p.y << 8));
        uint4 v2 = *(const uint4*)(xch + ((size_t)p.z << 8));
        uint4 v3 = *(const uint4*)(xch + ((size_t)p.w << 8));
        uint4 pk;
        {
            h2 r0 = (*(h2*)&v0.x) * qx + (*(h2*)&v1.x) * qy + (*(h2*)&v2.x) * qz + (*(h2*)&v3.x) * qv;
            h2 r1 = (*(h2*)&v0.y) * qx + (*(h2*)&v1.y) * qy + (*(h2*)&v2.y) * qz + (*(h2*)&v3.y) * qv;
            h2 r2 = (*(h2*)&v0.z) * qx + (*(h2*)&v1.z) * qy + (*(h2*)&v2.z) * qz + (*(h2*)&v3.z) * qv;
            h2 r3 = (*(h2*)&v0.w) * qx + (*(h2*)&v1.w) * qy + (*(h2*)&v2.w) * qz + (*(h2*)&v3.w) * qv;
            pk = make_uint4(*(unsigned*)&r0, *(unsigned*)&r1, *(unsigned*)&r2, *(unsigned*)&r3);
        }

        __syncthreads();
        *(uint4*)&s_a[oA      ][colA] = a0;
        *(uint4*)&s_a[oA +  64][colA] = a1;
        *(uint4*)&s_a[oA + 128][colA] = a2;
        *(uint4*)&s_a[oA + 192][colA] = a3;
        *(uint4*)&s_b[pxS][(chgS ^ (pxS & 7)) * 8] = pk;
        __syncthreads();

#pragma unroll
        for (int kf = 0; kf < 2; ++kf) {
            int oct = kf * 4 + kg;
            int bcol = (oct ^ (lm & 7)) * 8;
            f16x8 bf0 = *(const f16x8*)&s_b[wp * 32 + lm][bcol];
            f16x8 bf1 = *(const f16x8*)&s_b[wp * 32 + 16 + lm][bcol];
#pragma unroll
            for (int mi = 0; mi < 4; ++mi) {
                int o = wo * 64 + mi * 16 + lm;
                int col = (oct * 8) ^ ((o & 7) * 8);
                f16x8 af = *(const f16x8*)&s_a[o][col];
                acc[mi][0] = __builtin_amdgcn_mfma_f32_16x16x32_f16(af, bf0, acc[mi][0], 0, 0, 0);
                acc[mi][1] = __builtin_amdgcn_mfma_f32_16x16x32_f16(af, bf1, acc[mi][1], 0, 0, 0);
            }
        }
    }

    // epilogue: C/D col = lane&15 (px), row = kg*4 + reg (o)
    float* ob = out + ((size_t)b * 1024 + i * 256) * 4096;
#pragma unroll
    for (int mi = 0; mi < 4; ++mi) {
        int o = wo * 64 + mi * 16 + kg * 4;
#pragma unroll
        for (int ni = 0; ni < 2; ++ni) {
            int pg = px0 + wp * 32 + ni * 16 + lm;
#pragma unroll
            for (int reg = 0; reg < 4; ++reg)
                ob[(size_t)(o + reg) * 4096 + pg] = acc[mi][ni][reg];
        }
    }
}

extern "C" void kernel_launch(void* const* d_in, const int* in_sizes, int n_in,
                              void* d_out, int out_size, void* d_ws, size_t ws_size,
                              hipStream_t stream) {
    const float* x  = (const float*)d_in[0];   // [2,256,64,64]
    const float* dw = (const float*)d_in[1];   // [4,256,256,3,3]
    const float* ow = (const float*)d_in[2];   // [4,18,256,3,3]
    const float* ob = (const float*)d_in[3];   // [4,18]
    float* out = (float*)d_out;                // [2,1024,64,64]

    float* ws  = (float*)d_ws;
    float* off = ws;                                        // 589824 f32
    unsigned short* wTh  = (unsigned short*)(ws + 589824);  // 2359296 f16
    __hip_bfloat16* owTb = (__hip_bfloat16*)(wTh + 2359296);// 294912 bf16
    unsigned short* x16h = (unsigned short*)(ws + 1916928); // 2097152 f16 [b][pix][c]

    transpose_x_hwc_f16<<<512, 256, 0, stream>>>(x, x16h);
    transpose_dw_f16<<<9216, 256, 0, stream>>>(dw, wTh);
    transpose_ow_bf16<<<1152, 256, 0, stream>>>(ow, owTb);
    offset_mfma<<<256, 512, 0, stream>>>(x, owTb, ob, off);
    deform_mfma6<<<512, 512, 0, stream>>>(x16h, wTh, off, out);
}

// Round 10
// 113.917 us; speedup vs baseline: 2.5827x; 1.0458x over previous
//
#include <hip/hip_runtime.h>
#include <hip/hip_bf16.h>

typedef __attribute__((ext_vector_type(4))) float f32x4;
typedef __attribute__((ext_vector_type(2))) _Float16 h2;
typedef __attribute__((ext_vector_type(8))) _Float16 f16x8;

// ---------------- x [2][256][4096] f32 -> x16h [2][4096][256] f16 (HWC) ----------------
__global__ __launch_bounds__(256) void transpose_x_hwc_f16(const float* __restrict__ x,
                                                           unsigned short* __restrict__ x16h) {
    __shared__ float s[64][65];
    int blk = blockIdx.x;                 // 2 b * 4 ct * 64 pt = 512
    int b = blk >> 8, ct = (blk >> 6) & 3, pt = blk & 63;
    int c0 = ct * 64, p0 = pt * 64;
    int tid = threadIdx.x;
    int tr = tid >> 6, tc = tid & 63;
#pragma unroll
    for (int i = 0; i < 16; ++i) {
        int c = i * 4 + tr;
        s[c][tc] = x[((size_t)b * 256 + c0 + c) * 4096 + p0 + tc];
    }
    __syncthreads();
#pragma unroll
    for (int i = 0; i < 16; ++i) {
        int pp = i * 4 + tr;
        _Float16 h = (_Float16)s[tc][pp];
        x16h[((size_t)b * 4096 + p0 + pp) * 256 + c0 + tc] = *(unsigned short*)&h;
    }
}

// dweights [4][256][256][3][3] fp32 -> wTh [i][k][o][c] f16
__global__ __launch_bounds__(256) void transpose_dw_f16(const float* __restrict__ dw,
                                                        unsigned short* __restrict__ wTh) {
    int idx = blockIdx.x * 256 + threadIdx.x;      // 2359296
    int c = idx & 255;
    int o = (idx >> 8) & 255;
    int rest = idx >> 16;
    int k = rest % 9, i = rest / 9;
    _Float16 h = (_Float16)dw[(((i << 8) + o) * 256 + c) * 9 + k];
    wTh[idx] = *(unsigned short*)&h;
}

// oweights [4][18][256][3][3] fp32 -> owTh [r][k][32][256] f16 (rows 18..31 zero)
__global__ __launch_bounds__(256) void transpose_ow_f16(const float* __restrict__ ow,
                                                        unsigned short* __restrict__ owTh) {
    int idx = blockIdx.x * 256 + threadIdx.x;      // 294912
    int c = idx & 255;
    int m = (idx >> 8) & 31;
    int rk = idx >> 13;
    int k = rk % 9, r = rk / 9;
    float v = (m < 18) ? ow[((r * 18 + m) * 256 + c) * 9 + k] : 0.f;
    _Float16 h = (_Float16)v;
    owTh[idx] = *(unsigned short*)&h;
}

// ---------------- offset conv v2: f16 HWC dense staging + prefetch pipeline ----------------
// grid: 256 blocks; blk&7=(r,b), blk>>3 = 128-px tile. 512 threads = 8 waves.
// Tile: M=32 (18 used) x 128 px, K-step 32 (tap x 32ch), 72 steps.
__global__ __launch_bounds__(512) void offset_mfma2f(const unsigned short* __restrict__ x16h,
                                                     const unsigned short* __restrict__ owTh,
                                                     const float* __restrict__ obias,
                                                     float* __restrict__ off) {
    __shared__ short    s_a[4][32][8];
    __shared__ short    s_b[4][128][8];
    __shared__ int      s_pix[9][128];
    __shared__ unsigned s_msk[9][128];

    const int blk = blockIdx.x;
    const int r = (blk & 7) >> 1, b = blk & 1;
    const int px0 = (blk >> 3) << 7;
    const int rate = 6 * (r + 1);

    const int tid = threadIdx.x;
    const int lane = tid & 63;
    const int w = tid >> 6;
    const int kg = lane >> 4, lm = lane & 15;
    const int sg = tid >> 7, spx = tid & 127;
    const int mA = (tid & 127) >> 2, kgA = tid & 3;

    const unsigned short* xbh = x16h + (size_t)b * 1048576;   // [pix][256ch] f16
    const unsigned short* wrb = owTh + (size_t)r * 9 * 32 * 256;

    for (int e = tid; e < 1152; e += 512) {
        int k = e >> 7, pl = e & 127;
        int pg = px0 + pl;
        int yy = (pg >> 6) + (k / 3 - 1) * rate;
        int xx = (pg & 63) + (k % 3 - 1) * rate;
        bool v = ((unsigned)yy < 64u) && ((unsigned)xx < 64u);
        int cy = min(max(yy, 0), 63), cx = min(max(xx, 0), 63);
        s_pix[k][pl] = cy * 64 + cx;
        s_msk[k][pl] = v ? 0xFFFFFFFFu : 0u;
    }
    __syncthreads();

    f32x4 acc0 = (f32x4)(0.f), acc1 = (f32x4)(0.f);

    // prologue: issue loads for t=0
    uint4 a, v;
    if (tid < 128) a = *(const uint4*)(wrb + (size_t)mA * 256 + kgA * 8);
    {
        int pix = s_pix[0][spx];
        v = *(const uint4*)(xbh + (size_t)pix * 256 + sg * 8);
    }
    unsigned m = s_msk[0][spx];

    for (int t = 0; t < 72; ++t) {
        uint4 pk = make_uint4(v.x & m, v.y & m, v.z & m, v.w & m);

        __syncthreads();
        if (tid < 128) *(uint4*)&s_a[kgA][mA][0] = a;
        *(uint4*)&s_b[sg][spx][0] = pk;
        __syncthreads();

        if (t < 71) {   // issue loads for t+1 AFTER barrier2: fly during MFMA phase
            int tn = t + 1, tapn = tn >> 3, c0n = (tn & 7) << 5;
            if (tid < 128)
                a = *(const uint4*)(wrb + ((size_t)tapn * 32 + mA) * 256 + c0n + kgA * 8);
            int pix = s_pix[tapn][spx];
            m = s_msk[tapn][spx];
            v = *(const uint4*)(xbh + (size_t)pix * 256 + c0n + sg * 8);
        }

        f16x8 bf  = *(const f16x8*)&s_b[kg][w * 16 + lm][0];
        f16x8 af0 = *(const f16x8*)&s_a[kg][lm][0];
        f16x8 af1 = *(const f16x8*)&s_a[kg][16 + lm][0];
        acc0 = __builtin_amdgcn_mfma_f32_16x16x32_f16(af0, bf, acc0, 0, 0, 0);
        acc1 = __builtin_amdgcn_mfma_f32_16x16x32_f16(af1, bf, acc1, 0, 0, 0);
    }

    const float* bias = obias + r * 18;
    float* ob = off + (size_t)(r * 2 + b) * 18 * 4096;
    int px = px0 + w * 16 + lm;
#pragma unroll
    for (int reg = 0; reg < 4; ++reg) {
        int mm = kg * 4 + reg;
        ob[(size_t)mm * 4096 + px] = fmaxf(acc0[reg] + bias[mm], 0.f);
        int m1 = 16 + mm;
        if (m1 < 18)
            ob[(size_t)m1 * 4096 + px] = fmaxf(acc1[reg] + bias[m1], 0.f);
    }
}

// ---------------- deformable conv v7: HWC gather + f16 lerp/MFMA + T14 prefetch ----------------
// grid: 512 blocks; blk&7 = (i,b), blk>>3 = 64-px tile. 512 threads = 8 waves.
// Loads for step t+1 issued right AFTER barrier2 of step t (post-barrier => the
// __syncthreads vmcnt(0) drain sees nothing outstanding; latency hides under MFMA).
__global__ __launch_bounds__(512, 2) void deform_mfma7(const unsigned short* __restrict__ x16h,
                                                       const unsigned short* __restrict__ wTh,
                                                       const float* __restrict__ off,
                                                       float* __restrict__ out) {
    __shared__ short  s_a[256][64];     // [o][64 step-ch], col ^= (o&7)*8 swizzle  32 KB
    __shared__ short  s_b[64][64];      // [px][oct^(px&7) octets of 8ch]            8 KB
    __shared__ int4   s_pix[9][64];
    __shared__ float4 s_wt[9][64];

    const int blk = blockIdx.x;
    const int i = (blk & 7) >> 1, b = blk & 1;
    const int px0 = (blk >> 3) << 6;
    const int r = (i + 3) & 3;
    const int rate = 6 * (i + 1);

    const int tid = threadIdx.x;
    const int lane = tid & 63;
    const int w = tid >> 6;
    const int wo = w >> 1, wp = w & 1;
    const int kg = lane >> 4, lm = lane & 15;
    const int pxS = tid >> 3, chgS = tid & 7;
    const int oA = tid >> 3, partA = tid & 7;
    const int colA = (partA * 8) ^ ((oA & 7) * 8);

    const unsigned short* xbh = x16h + (size_t)b * 1048576;
    const float* offb = off + (size_t)(r * 2 + b) * 18 * 4096;
    const unsigned short* wib = wTh + (size_t)i * 9 * 65536;

    for (int e = tid; e < 576; e += 512) {
        int k = e >> 6, pl = e & 63;
        int pg = px0 + pl;
        int yy = pg >> 6, xc = pg & 63;
        float dy = offb[(size_t)(2 * k) * 4096 + pg];
        float dx = offb[(size_t)(2 * k + 1) * 4096 + pg];
        float py = (float)(yy + (k / 3 - 1) * rate) + dy;
        float pxf = (float)(xc + (k % 3 - 1) * rate) + dx;
        float fy = floorf(py), fx = floorf(pxf);
        int y0 = (int)fy, x0 = (int)fx;
        float wy = py - fy, wx = pxf - fx;
        float vy0 = ((unsigned)y0 < 64u) ? 1.f : 0.f;
        float vy1 = ((unsigned)(y0 + 1) < 64u) ? 1.f : 0.f;
        float vx0 = ((unsigned)x0 < 64u) ? 1.f : 0.f;
        float vx1 = ((unsigned)(x0 + 1) < 64u) ? 1.f : 0.f;
        int cy0 = min(max(y0, 0), 63), cy1 = min(max(y0 + 1, 0), 63);
        int cx0 = min(max(x0, 0), 63), cx1 = min(max(x0 + 1, 0), 63);
        s_pix[k][pl] = make_int4(cy0 * 64 + cx0, cy0 * 64 + cx1,
                                 cy1 * 64 + cx0, cy1 * 64 + cx1);
        s_wt[k][pl] = make_float4(vy0 * vx0 * (1.f - wy) * (1.f - wx),
                                  vy0 * vx1 * (1.f - wy) * wx,
                                  vy1 * vx0 * wy * (1.f - wx),
                                  vy1 * vx1 * wy * wx);
    }
    __syncthreads();

    f32x4 acc[4][2];
#pragma unroll
    for (int mi = 0; mi < 4; ++mi) {
        acc[mi][0] = (f32x4)(0.f);
        acc[mi][1] = (f32x4)(0.f);
    }

    // prologue: issue loads for t=0
    uint4 a0, a1, a2, a3, v0, v1, v2, v3;
    {
        const unsigned short* wrow = wib + partA * 8;
        a0 = *(const uint4*)(wrow + (size_t)(oA      ) * 256);
        a1 = *(const uint4*)(wrow + (size_t)(oA +  64) * 256);
        a2 = *(const uint4*)(wrow + (size_t)(oA + 128) * 256);
        a3 = *(const uint4*)(wrow + (size_t)(oA + 192) * 256);
        int4 p = s_pix[0][pxS];
        const unsigned short* xch = xbh + chgS * 8;
        v0 = *(const uint4*)(xch + ((size_t)p.x << 8));
        v1 = *(const uint4*)(xch + ((size_t)p.y << 8));
        v2 = *(const uint4*)(xch + ((size_t)p.z << 8));
        v3 = *(const uint4*)(xch + ((size_t)p.w << 8));
    }

    for (int t = 0; t < 36; ++t) {
        const int tap = t >> 2;

        // lerp current step's corners (packed f16)
        uint4 pk;
        {
            float4 qwf = s_wt[tap][pxS];
            h2 qx = (h2)((_Float16)qwf.x), qy = (h2)((_Float16)qwf.y);
            h2 qz = (h2)((_Float16)qwf.z), qv = (h2)((_Float16)qwf.w);
            h2 r0 = (*(h2*)&v0.x) * qx + (*(h2*)&v1.x) * qy + (*(h2*)&v2.x) * qz + (*(h2*)&v3.x) * qv;
            h2 r1 = (*(h2*)&v0.y) * qx + (*(h2*)&v1.y) * qy + (*(h2*)&v2.y) * qz + (*(h2*)&v3.y) * qv;
            h2 r2 = (*(h2*)&v0.z) * qx + (*(h2*)&v1.z) * qy + (*(h2*)&v2.z) * qz + (*(h2*)&v3.z) * qv;
            h2 r3 = (*(h2*)&v0.w) * qx + (*(h2*)&v1.w) * qy + (*(h2*)&v2.w) * qz + (*(h2*)&v3.w) * qv;
            pk = make_uint4(*(unsigned*)&r0, *(unsigned*)&r1, *(unsigned*)&r2, *(unsigned*)&r3);
        }

        __syncthreads();
        *(uint4*)&s_a[oA      ][colA] = a0;
        *(uint4*)&s_a[oA +  64][colA] = a1;
        *(uint4*)&s_a[oA + 128][colA] = a2;
        *(uint4*)&s_a[oA + 192][colA] = a3;
        *(uint4*)&s_b[pxS][(chgS ^ (pxS & 7)) * 8] = pk;
        __syncthreads();

        if (t < 35) {   // issue t+1 loads after barrier2 -> overlap with MFMA phase
            int tn = t + 1, tapn = tn >> 2, c0n = (tn & 3) << 6;
            const unsigned short* wrow = wib + (size_t)tapn * 65536 + c0n + partA * 8;
            a0 = *(const uint4*)(wrow + (size_t)(oA      ) * 256);
            a1 = *(const uint4*)(wrow + (size_t)(oA +  64) * 256);
            a2 = *(const uint4*)(wrow + (size_t)(oA + 128) * 256);
            a3 = *(const uint4*)(wrow + (size_t)(oA + 192) * 256);
            int4 p = s_pix[tapn][pxS];
            const unsigned short* xch = xbh + c0n + chgS * 8;
            v0 = *(const uint4*)(xch + ((size_t)p.x << 8));
            v1 = *(const uint4*)(xch + ((size_t)p.y << 8));
            v2 = *(const uint4*)(xch + ((size_t)p.z << 8));
            v3 = *(const uint4*)(xch + ((size_t)p.w << 8));
        }

#pragma unroll
        for (int kf = 0; kf < 2; ++kf) {
            int oct = kf * 4 + kg;
            int bcol = (oct ^ (lm & 7)) * 8;
            f16x8 bf0 = *(const f16x8*)&s_b[wp * 32 + lm][bcol];
            f16x8 bf1 = *(const f16x8*)&s_b[wp * 32 + 16 + lm][bcol];
#pragma unroll
            for (int mi = 0; mi < 4; ++mi) {
                int o = wo * 64 + mi * 16 + lm;
                int col = (oct * 8) ^ ((o & 7) * 8);
                f16x8 af = *(const f16x8*)&s_a[o][col];
                acc[mi][0] = __builtin_amdgcn_mfma_f32_16x16x32_f16(af, bf0, acc[mi][0], 0, 0, 0);
                acc[mi][1] = __builtin_amdgcn_mfma_f32_16x16x32_f16(af, bf1, acc[mi][1], 0, 0, 0);
            }
        }
    }

    // epilogue: C/D col = lane&15 (px), row = kg*4 + reg (o)
    float* ob = out + ((size_t)b * 1024 + i * 256) * 4096;
#pragma unroll
    for (int mi = 0; mi < 4; ++mi) {
        int o = wo * 64 + mi * 16 + kg * 4;
#pragma unroll
        for (int ni = 0; ni < 2; ++ni) {
            int pg = px0 + wp * 32 + ni * 16 + lm;
#pragma unroll
            for (int reg = 0; reg < 4; ++reg)
                ob[(size_t)(o + reg) * 4096 + pg] = acc[mi][ni][reg];
        }
    }
}

extern "C" void kernel_launch(void* const* d_in, const int* in_sizes, int n_in,
                              void* d_out, int out_size, void* d_ws, size_t ws_size,
                              hipStream_t stream) {
    const float* x  = (const float*)d_in[0];   // [2,256,64,64]
    const float* dw = (const float*)d_in[1];   // [4,256,256,3,3]
    const float* ow = (const float*)d_in[2];   // [4,18,256,3,3]
    const float* ob = (const float*)d_in[3];   // [4,18]
    float* out = (float*)d_out;                // [2,1024,64,64]

    float* ws  = (float*)d_ws;
    float* off = ws;                                        // 589824 f32
    unsigned short* wTh  = (unsigned short*)(ws + 589824);  // 2359296 f16
    unsigned short* owTh = wTh + 2359296;                   // 294912 f16
    unsigned short* x16h = (unsigned short*)(ws + 1916928); // 2097152 f16 [b][pix][c]

    transpose_x_hwc_f16<<<512, 256, 0, stream>>>(x, x16h);
    transpose_dw_f16<<<9216, 256, 0, stream>>>(dw, wTh);
    transpose_ow_f16<<<1152, 256, 0, stream>>>(ow, owTh);
    offset_mfma2f<<<256, 512, 0, stream>>>(x16h, owTh, ob, off);
    deform_mfma7<<<512, 512, 0, stream>>>(x16h, wTh, off, out);
}